// Round 2
// baseline (408.558 us; speedup 1.0000x reference)
//
#include <hip/hip_runtime.h>

#define NG 512
#define HID 64

// Each node's CSR segment is padded to a multiple of 8; pad slots hold src=N,
// which indexes a zero row in xs2 / h2, so pads contribute nothing.
__device__ __forceinline__ int pad8(int d) { return (d + 7) & ~7; }

// ---------------- degree ----------------
__global__ void deg_kernel(const int* __restrict__ dst, int* __restrict__ deg, int E) {
    int e = blockIdx.x * blockDim.x + threadIdx.x;
    if (e < E) atomicAdd(&deg[dst[e]], 1);
}

// ---------------- CSR build (padded) ----------------
__global__ void block_sums_kernel(const int* __restrict__ deg, int* __restrict__ bsum, int N) {
    __shared__ int s[256];
    int i = blockIdx.x * 256 + threadIdx.x;
    s[threadIdx.x] = (i < N) ? pad8(deg[i]) : 0;
    __syncthreads();
    for (int off = 128; off > 0; off >>= 1) {
        if (threadIdx.x < off) s[threadIdx.x] += s[threadIdx.x + off];
        __syncthreads();
    }
    if (threadIdx.x == 0) bsum[blockIdx.x] = s[0];
}

__global__ __launch_bounds__(1024) void scan_bsum_kernel(const int* __restrict__ bsum,
                                                         int* __restrict__ bofs, int nb) {
    __shared__ int s[1024];
    __shared__ int carry;
    if (threadIdx.x == 0) carry = 0;
    __syncthreads();
    for (int base = 0; base < nb; base += 1024) {
        int i = base + threadIdx.x;
        int v = (i < nb) ? bsum[i] : 0;
        s[threadIdx.x] = v;
        __syncthreads();
        for (int off = 1; off < 1024; off <<= 1) {
            int t = (threadIdx.x >= off) ? s[threadIdx.x - off] : 0;
            __syncthreads();
            s[threadIdx.x] += t;
            __syncthreads();
        }
        if (i < nb) bofs[i] = carry + s[threadIdx.x] - v;  // exclusive
        __syncthreads();
        if (threadIdx.x == 1023) carry += s[1023];
        __syncthreads();
    }
}

// Also emits: dinv, xs2 = x * dinv (zero row at N), pad-slot fill (src=N),
// rowptr[N] = padded total, and per-graph node counts (gcnt) so layer2
// doesn't need a second atomic per node.
__global__ void scan_block_kernel(const int* __restrict__ deg, const int* __restrict__ bofs,
                                  const float2* __restrict__ x2, const int* __restrict__ batch,
                                  int* __restrict__ rowptr, float* __restrict__ dinv,
                                  float2* __restrict__ xs2, int* __restrict__ esrc,
                                  int* __restrict__ gcnt, int N) {
    __shared__ int tmp[256];
    int i = blockIdx.x * 256 + threadIdx.x;
    int d = (i < N) ? deg[i] : 0;
    int vp = pad8(d);
    tmp[threadIdx.x] = vp;
    __syncthreads();
    for (int off = 1; off < 256; off <<= 1) {
        int t = (threadIdx.x >= off) ? tmp[threadIdx.x - off] : 0;
        __syncthreads();
        tmp[threadIdx.x] += t;
        __syncthreads();
    }
    if (i < N) {
        int start = bofs[blockIdx.x] + tmp[threadIdx.x] - vp;  // exclusive (padded space)
        rowptr[i] = start;
        float di = rsqrtf((float)d + 1.0f);
        dinv[i] = di;
        float2 xv = x2[i];
        xs2[i] = make_float2(xv.x * di, xv.y * di);
        for (int j = d; j < vp; ++j) esrc[start + j] = N;  // pads -> zero row
        atomicAdd(&gcnt[batch[i]], 1);
        if (i == N - 1) rowptr[N] = start + vp;
    }
    if (i == 0) xs2[N] = make_float2(0.0f, 0.0f);
}

__global__ void bucket_kernel(const int* __restrict__ src, const int* __restrict__ dst,
                              const int* __restrict__ rowptr, int* __restrict__ cur,
                              int* __restrict__ esrc, int E) {
    int e = blockIdx.x * blockDim.x + threadIdx.x;
    if (e >= E) return;
    int d = dst[e];
    int p = rowptr[d] + atomicAdd(&cur[d], 1);
    esrc[p] = src[e];
}

// ---------------- layer 1 (fused W2): h2 = (relu((A xs)@W1 + b1) * dinv) @ W2 ----
// One wave per node, lane = feature. The W2 matvec is hoisted HERE (linear op
// commutes with the layer-2 aggregation: agg@W2 = dinv * sum(h2_src)), so the
// latency-critical layer-2 gather kernel is a pure sum. Matvec uses readlane
// (SGPR broadcast) + conflict-free LDS Ws reads.
__global__ __launch_bounds__(256) void layer1_kernel(
    const float2* __restrict__ xs2, const int* __restrict__ rowptr,
    const int* __restrict__ esrc, const float* __restrict__ dinv,
    const float* __restrict__ W1, const float* __restrict__ b1,
    const float* __restrict__ W2, float* __restrict__ h2, int N) {
    __shared__ float Ws[HID * HID];  // k-major: Ws[k*64+j]
    {
        float4* Ws4 = (float4*)Ws;
        const float4* W24 = (const float4*)W2;
        for (int t = threadIdx.x; t < HID * HID / 4; t += 256) Ws4[t] = W24[t];
    }
    __syncthreads();
    int t = blockIdx.x * blockDim.x + threadIdx.x;
    int node = t >> 6, lane = t & 63;
    if (node > N) return;
    if (node == N) { h2[(size_t)N * HID + lane] = 0.0f; return; }
    int un = __builtin_amdgcn_readfirstlane(node);
    int k0 = __builtin_amdgcn_readfirstlane(rowptr[un]);
    int k1 = __builtin_amdgcn_readfirstlane(rowptr[un + 1]);
    float a0 = 0.0f, a1 = 0.0f;
    for (int e = k0; e < k1; e += 8) {
        const int4* ep = (const int4*)(esrc + e);  // 32B-aligned (rowptr % 8 == 0)
        int4 qa = ep[0], qb = ep[1];
        float2 v0 = xs2[qa.x], v1 = xs2[qa.y], v2 = xs2[qa.z], v3 = xs2[qa.w];
        float2 v4 = xs2[qb.x], v5 = xs2[qb.y], v6 = xs2[qb.z], v7 = xs2[qb.w];
        a0 += ((v0.x + v1.x) + (v2.x + v3.x)) + ((v4.x + v5.x) + (v6.x + v7.x));
        a1 += ((v0.y + v1.y) + (v2.y + v3.y)) + ((v4.y + v5.y) + (v6.y + v7.y));
    }
    float di = dinv[un];
    float2 xn = xs2[un];
    float m0 = di * (a0 + xn.x);  // = di*sum(x_s*di_s) + x_n*di^2
    float m1 = di * (a1 + xn.y);
    float v = fmaf(m0, W1[lane], fmaf(m1, W1[HID + lane], b1[lane]));
    float h1s = fmaxf(v, 0.0f) * di;  // h1 * dinv, lane = feature k
    // h2[j] = sum_k h1s[k] * W2[k][j]
    float z = 0.0f;
#pragma unroll
    for (int k = 0; k < HID; ++k) {
        float hk = __int_as_float(__builtin_amdgcn_readlane(__float_as_int(h1s), k));
        z = fmaf(hk, Ws[k * HID + lane], z);
    }
    h2[(size_t)un * HID + lane] = z;
}

// ---------------- layer 2: pure gather-sum + pool ----------------
// z_d = relu(dinv_d * (sum_{s->d} h2_s + h2_d) + b2); atomic mean-pool accumulate.
// No LDS, no per-node matvec: the wave spends its whole node on issuing row
// gathers (16 in flight, 1 VGPR each). (256,8): 64-VGPR cap -> 8 blocks/CU
// eligible (loop needs ~44 regs), double the resident waves of the (256,4) version.
__global__ __launch_bounds__(256, 8) void layer2_kernel(
    const int* __restrict__ rowptr, const int* __restrict__ esrc,
    const float* __restrict__ dinv, const float* __restrict__ h2,
    const float* __restrict__ b2, const int* __restrict__ batch,
    float* __restrict__ gsum, int N) {
    int lane = threadIdx.x & 63;
    float bz = b2[lane];
    int wave = (blockIdx.x * 256 + threadIdx.x) >> 6;
    int nwaves = gridDim.x * 4;
    for (int node = wave; node < N; node += nwaves) {
        int un = __builtin_amdgcn_readfirstlane(node);
        int k0 = __builtin_amdgcn_readfirstlane(rowptr[un]);
        int k1 = __builtin_amdgcn_readfirstlane(rowptr[un + 1]);
        float acc = h2[(un << 6) + lane];  // self term
        int e = k0;
        for (; e + 16 <= k1; e += 16) {  // 16 row-gathers in flight
            const int4* ep = (const int4*)(esrc + e);
            int4 qa = ep[0], qb = ep[1], qc = ep[2], qd = ep[3];
            float r0 = h2[(qa.x << 6) + lane], r1 = h2[(qa.y << 6) + lane];
            float r2 = h2[(qa.z << 6) + lane], r3 = h2[(qa.w << 6) + lane];
            float r4 = h2[(qb.x << 6) + lane], r5 = h2[(qb.y << 6) + lane];
            float r6 = h2[(qb.z << 6) + lane], r7 = h2[(qb.w << 6) + lane];
            float r8 = h2[(qc.x << 6) + lane], r9 = h2[(qc.y << 6) + lane];
            float r10 = h2[(qc.z << 6) + lane], r11 = h2[(qc.w << 6) + lane];
            float r12 = h2[(qd.x << 6) + lane], r13 = h2[(qd.y << 6) + lane];
            float r14 = h2[(qd.z << 6) + lane], r15 = h2[(qd.w << 6) + lane];
            acc += (((r0 + r1) + (r2 + r3)) + ((r4 + r5) + (r6 + r7)))
                 + (((r8 + r9) + (r10 + r11)) + ((r12 + r13) + (r14 + r15)));
        }
        if (e < k1) {  // exactly 8 remain (segments are multiples of 8)
            const int4* ep = (const int4*)(esrc + e);
            int4 qa = ep[0], qb = ep[1];
            float r0 = h2[(qa.x << 6) + lane], r1 = h2[(qa.y << 6) + lane];
            float r2 = h2[(qa.z << 6) + lane], r3 = h2[(qa.w << 6) + lane];
            float r4 = h2[(qb.x << 6) + lane], r5 = h2[(qb.y << 6) + lane];
            float r6 = h2[(qb.z << 6) + lane], r7 = h2[(qb.w << 6) + lane];
            acc += ((r0 + r1) + (r2 + r3)) + ((r4 + r5) + (r6 + r7));
        }
        float z = fmaxf(fmaf(dinv[un], acc, bz), 0.0f);
        atomicAdd(&gsum[(batch[un] << 6) + lane], z);
    }
}

// ---------------- head ----------------
__global__ void head_kernel(const float* __restrict__ gsum, const int* __restrict__ gcnt,
                            const float* __restrict__ Wf1, const float* __restrict__ bf1,
                            const float* __restrict__ Wf2, const float* __restrict__ bf2,
                            float* __restrict__ out) {
    __shared__ float gs[HID];
    __shared__ float ts[HID];
    int b = blockIdx.x;
    int j = threadIdx.x;
    float cnt = fmaxf((float)gcnt[b], 1.0f);
    gs[j] = gsum[b * HID + j] / cnt;
    __syncthreads();
    float acc = bf1[j];
#pragma unroll
    for (int k = 0; k < HID; ++k) acc = fmaf(gs[k], Wf1[k * HID + j], acc);
    ts[j] = fmaxf(acc, 0.0f);
    __syncthreads();
    if (j < 4) {
        float o = bf2[j];
#pragma unroll
        for (int k = 0; k < HID; ++k) o = fmaf(ts[k], Wf2[k * 4 + j], o);
        out[b * 4 + j] = o;
    }
}

extern "C" void kernel_launch(void* const* d_in, const int* in_sizes, int n_in,
                              void* d_out, int out_size, void* d_ws, size_t ws_size,
                              hipStream_t stream) {
    const float* x   = (const float*)d_in[0];
    const int*   ei  = (const int*)d_in[1];
    const int*   bat = (const int*)d_in[2];
    const float* W1  = (const float*)d_in[4];
    const float* b1  = (const float*)d_in[5];
    const float* W2  = (const float*)d_in[6];
    const float* b2  = (const float*)d_in[7];
    const float* Wf1 = (const float*)d_in[8];
    const float* bf1 = (const float*)d_in[9];
    const float* Wf2 = (const float*)d_in[10];
    const float* bf2 = (const float*)d_in[11];
    float* out = (float*)d_out;

    int N = in_sizes[2];
    int E = in_sizes[1] / 2;
    const int* src = ei;
    const int* dst = ei + E;
    int nb = (N + 255) / 256;
    size_t Ecap = (size_t)E + 7 * (size_t)N + 8;  // padded-CSR upper bound

    char* ws = (char*)d_ws;
    size_t off = 0;
    auto alloc = [&](size_t bytes) {
        char* p = ws + off;
        off = (off + bytes + 255) & ~(size_t)255;
        return p;
    };
    int*    deg    = (int*)alloc((size_t)N * 4);
    int*    cur    = (int*)alloc((size_t)N * 4);
    float*  dinv   = (float*)alloc((size_t)N * 4);
    int*    rowptr = (int*)alloc((size_t)(N + 1) * 4);
    int*    bsum   = (int*)alloc((size_t)nb * 4);
    int*    bofs   = (int*)alloc((size_t)nb * 4);
    int*    esrc   = (int*)alloc(Ecap * 4);
    float2* xs2    = (float2*)alloc((size_t)(N + 1) * 8);
    float*  h2buf  = (float*)alloc((size_t)(N + 1) * HID * 4);
    float*  gsum   = (float*)alloc((size_t)NG * HID * 4);
    int*    gcnt   = (int*)alloc((size_t)NG * 4);

    hipMemsetAsync(deg, 0, (size_t)((char*)cur - (char*)deg) + (size_t)N * 4, stream);
    hipMemsetAsync(gsum, 0, (size_t)((char*)gcnt - (char*)gsum) + (size_t)NG * 4, stream);

    deg_kernel<<<(E + 255) / 256, 256, 0, stream>>>(dst, deg, E);
    block_sums_kernel<<<nb, 256, 0, stream>>>(deg, bsum, N);
    scan_bsum_kernel<<<1, 1024, 0, stream>>>(bsum, bofs, nb);
    scan_block_kernel<<<nb, 256, 0, stream>>>(deg, bofs, (const float2*)x, bat, rowptr,
                                              dinv, xs2, esrc, gcnt, N);
    bucket_kernel<<<(E + 255) / 256, 256, 0, stream>>>(src, dst, rowptr, cur, esrc, E);

    // layer 1 (+ fused W2): h2 = (relu((A xs)@W1 + b1) * dinv) @ W2   (+ zero pad row)
    int nh = (N + 1) * HID;
    layer1_kernel<<<(nh + 255) / 256, 256, 0, stream>>>(xs2, rowptr, esrc, dinv, W1, b1,
                                                        W2, h2buf, N);

    // layer 2: pure gather-sum -> relu -> pool
    layer2_kernel<<<8192, 256, 0, stream>>>(rowptr, esrc, dinv, h2buf, b2, bat, gsum, N);

    head_kernel<<<NG, HID, 0, stream>>>(gsum, gcnt, Wf1, bf1, Wf2, bf2, out);
}

// Round 3
// 323.544 us; speedup vs baseline: 1.2628x; 1.2628x over previous
//
#include <hip/hip_runtime.h>

#define NG 512
#define HID 64

// Each node's CSR segment is padded to a multiple of 8; pad slots hold src=N,
// which indexes a zero row in xs2 / h2, so pads contribute nothing.
__device__ __forceinline__ int pad8(int d) { return (d + 7) & ~7; }

// ---------------- degree ----------------
__global__ void deg_kernel(const int* __restrict__ dst, int* __restrict__ deg, int E) {
    int e = blockIdx.x * blockDim.x + threadIdx.x;
    if (e < E) atomicAdd(&deg[dst[e]], 1);
}

// ---------------- esrc pre-fill: every slot = N (pads resolved for free) ----
__global__ void fill_esrc_kernel(int4* __restrict__ esrc4, int v, int n4) {
    int i = blockIdx.x * blockDim.x + threadIdx.x;
    if (i < n4) esrc4[i] = make_int4(v, v, v, v);
}

// ---------------- per-graph segment starts (batch is sorted; NO atomics) ----
// gstart[g] = first node index with batch >= g; gstart[NG] = N.
// Per-graph count = gstart[g+1] - gstart[g].
__global__ void gstart_kernel(const int* __restrict__ batch, int* __restrict__ gstart, int N) {
    int i = blockIdx.x * blockDim.x + threadIdx.x;
    if (i >= N) return;
    int b = batch[i];
    int bp = (i == 0) ? -1 : batch[i - 1];
    for (int g = bp + 1; g <= b; ++g) gstart[g] = i;   // boundaries only (rare)
    if (i == N - 1)
        for (int g = b + 1; g <= NG; ++g) gstart[g] = N;
}

// ---------------- CSR build (padded) ----------------
__global__ void block_sums_kernel(const int* __restrict__ deg, int* __restrict__ bsum, int N) {
    __shared__ int s[256];
    int i = blockIdx.x * 256 + threadIdx.x;
    s[threadIdx.x] = (i < N) ? pad8(deg[i]) : 0;
    __syncthreads();
    for (int off = 128; off > 0; off >>= 1) {
        if (threadIdx.x < off) s[threadIdx.x] += s[threadIdx.x + off];
        __syncthreads();
    }
    if (threadIdx.x == 0) bsum[blockIdx.x] = s[0];
}

__global__ __launch_bounds__(1024) void scan_bsum_kernel(const int* __restrict__ bsum,
                                                         int* __restrict__ bofs, int nb) {
    __shared__ int s[1024];
    __shared__ int carry;
    if (threadIdx.x == 0) carry = 0;
    __syncthreads();
    for (int base = 0; base < nb; base += 1024) {
        int i = base + threadIdx.x;
        int v = (i < nb) ? bsum[i] : 0;
        s[threadIdx.x] = v;
        __syncthreads();
        for (int off = 1; off < 1024; off <<= 1) {
            int t = (threadIdx.x >= off) ? s[threadIdx.x - off] : 0;
            __syncthreads();
            s[threadIdx.x] += t;
            __syncthreads();
        }
        if (i < nb) bofs[i] = carry + s[threadIdx.x] - v;  // exclusive
        __syncthreads();
        if (threadIdx.x == 1023) carry += s[1023];
        __syncthreads();
    }
}

// Lean: emits rowptr (padded space), dinv, xs2 = x * dinv (zero row at N).
// No esrc writes, no atomics here (both were ~90us of serialization in R2).
__global__ void scan_block_kernel(const int* __restrict__ deg, const int* __restrict__ bofs,
                                  const float2* __restrict__ x2,
                                  int* __restrict__ rowptr, float* __restrict__ dinv,
                                  float2* __restrict__ xs2, int N) {
    __shared__ int tmp[256];
    int i = blockIdx.x * 256 + threadIdx.x;
    int d = (i < N) ? deg[i] : 0;
    int vp = pad8(d);
    tmp[threadIdx.x] = vp;
    __syncthreads();
    for (int off = 1; off < 256; off <<= 1) {
        int t = (threadIdx.x >= off) ? tmp[threadIdx.x - off] : 0;
        __syncthreads();
        tmp[threadIdx.x] += t;
        __syncthreads();
    }
    if (i < N) {
        int start = bofs[blockIdx.x] + tmp[threadIdx.x] - vp;  // exclusive (padded space)
        rowptr[i] = start;
        float di = rsqrtf((float)d + 1.0f);
        dinv[i] = di;
        float2 xv = x2[i];
        xs2[i] = make_float2(xv.x * di, xv.y * di);
        if (i == N - 1) rowptr[N] = start + vp;
    }
    if (i == 0) xs2[N] = make_float2(0.0f, 0.0f);
}

__global__ void bucket_kernel(const int* __restrict__ src, const int* __restrict__ dst,
                              const int* __restrict__ rowptr, int* __restrict__ cur,
                              int* __restrict__ esrc, int E) {
    int e = blockIdx.x * blockDim.x + threadIdx.x;
    if (e >= E) return;
    int d = dst[e];
    int p = rowptr[d] + atomicAdd(&cur[d], 1);
    esrc[p] = src[e];
}

// ---------------- layer 1 (fused W2): h2 = (relu((A xs)@W1 + b1) * dinv) @ W2 ----
// One wave per node, lane = feature. The W2 matvec is hoisted HERE (linear op
// commutes with the layer-2 aggregation: agg@W2 = dinv * sum(h2_src)), so the
// latency-critical layer-2 gather kernel is a pure sum.
__global__ __launch_bounds__(256) void layer1_kernel(
    const float2* __restrict__ xs2, const int* __restrict__ rowptr,
    const int* __restrict__ esrc, const float* __restrict__ dinv,
    const float* __restrict__ W1, const float* __restrict__ b1,
    const float* __restrict__ W2, float* __restrict__ h2, int N) {
    __shared__ float Ws[HID * HID];  // k-major: Ws[k*64+j]
    {
        float4* Ws4 = (float4*)Ws;
        const float4* W24 = (const float4*)W2;
        for (int t = threadIdx.x; t < HID * HID / 4; t += 256) Ws4[t] = W24[t];
    }
    __syncthreads();
    int t = blockIdx.x * blockDim.x + threadIdx.x;
    int node = t >> 6, lane = t & 63;
    if (node > N) return;
    if (node == N) { h2[(size_t)N * HID + lane] = 0.0f; return; }
    int un = __builtin_amdgcn_readfirstlane(node);
    int k0 = __builtin_amdgcn_readfirstlane(rowptr[un]);
    int k1 = __builtin_amdgcn_readfirstlane(rowptr[un + 1]);
    float a0 = 0.0f, a1 = 0.0f;
    for (int e = k0; e < k1; e += 8) {
        const int4* ep = (const int4*)(esrc + e);  // 32B-aligned (rowptr % 8 == 0)
        int4 qa = ep[0], qb = ep[1];
        float2 v0 = xs2[qa.x], v1 = xs2[qa.y], v2 = xs2[qa.z], v3 = xs2[qa.w];
        float2 v4 = xs2[qb.x], v5 = xs2[qb.y], v6 = xs2[qb.z], v7 = xs2[qb.w];
        a0 += ((v0.x + v1.x) + (v2.x + v3.x)) + ((v4.x + v5.x) + (v6.x + v7.x));
        a1 += ((v0.y + v1.y) + (v2.y + v3.y)) + ((v4.y + v5.y) + (v6.y + v7.y));
    }
    float di = dinv[un];
    float2 xn = xs2[un];
    float m0 = di * (a0 + xn.x);  // = di*sum(x_s*di_s) + x_n*di^2
    float m1 = di * (a1 + xn.y);
    float v = fmaf(m0, W1[lane], fmaf(m1, W1[HID + lane], b1[lane]));
    float h1s = fmaxf(v, 0.0f) * di;  // h1 * dinv, lane = feature k
    // h2[j] = sum_k h1s[k] * W2[k][j]
    float z = 0.0f;
#pragma unroll
    for (int k = 0; k < HID; ++k) {
        float hk = __int_as_float(__builtin_amdgcn_readlane(__float_as_int(h1s), k));
        z = fmaf(hk, Ws[k * HID + lane], z);
    }
    h2[(size_t)un * HID + lane] = z;
}

// ---------------- layer 2: pure gather-sum + pool ----------------
// z_d = relu(dinv_d * (sum_{s->d} h2_s + h2_d) + b2); atomic mean-pool accumulate.
// No LDS, no per-node matvec: the wave spends its whole node on issuing row
// gathers (16 in flight, 1 VGPR each). (256,8): 64-VGPR cap -> 8 blocks/CU.
__global__ __launch_bounds__(256, 8) void layer2_kernel(
    const int* __restrict__ rowptr, const int* __restrict__ esrc,
    const float* __restrict__ dinv, const float* __restrict__ h2,
    const float* __restrict__ b2, const int* __restrict__ batch,
    float* __restrict__ gsum, int N) {
    int lane = threadIdx.x & 63;
    float bz = b2[lane];
    int wave = (blockIdx.x * 256 + threadIdx.x) >> 6;
    int nwaves = gridDim.x * 4;
    for (int node = wave; node < N; node += nwaves) {
        int un = __builtin_amdgcn_readfirstlane(node);
        int k0 = __builtin_amdgcn_readfirstlane(rowptr[un]);
        int k1 = __builtin_amdgcn_readfirstlane(rowptr[un + 1]);
        float acc = h2[(un << 6) + lane];  // self term
        int e = k0;
        for (; e + 16 <= k1; e += 16) {  // 16 row-gathers in flight
            const int4* ep = (const int4*)(esrc + e);
            int4 qa = ep[0], qb = ep[1], qc = ep[2], qd = ep[3];
            float r0 = h2[(qa.x << 6) + lane], r1 = h2[(qa.y << 6) + lane];
            float r2 = h2[(qa.z << 6) + lane], r3 = h2[(qa.w << 6) + lane];
            float r4 = h2[(qb.x << 6) + lane], r5 = h2[(qb.y << 6) + lane];
            float r6 = h2[(qb.z << 6) + lane], r7 = h2[(qb.w << 6) + lane];
            float r8 = h2[(qc.x << 6) + lane], r9 = h2[(qc.y << 6) + lane];
            float r10 = h2[(qc.z << 6) + lane], r11 = h2[(qc.w << 6) + lane];
            float r12 = h2[(qd.x << 6) + lane], r13 = h2[(qd.y << 6) + lane];
            float r14 = h2[(qd.z << 6) + lane], r15 = h2[(qd.w << 6) + lane];
            acc += (((r0 + r1) + (r2 + r3)) + ((r4 + r5) + (r6 + r7)))
                 + (((r8 + r9) + (r10 + r11)) + ((r12 + r13) + (r14 + r15)));
        }
        if (e < k1) {  // exactly 8 remain (segments are multiples of 8)
            const int4* ep = (const int4*)(esrc + e);
            int4 qa = ep[0], qb = ep[1];
            float r0 = h2[(qa.x << 6) + lane], r1 = h2[(qa.y << 6) + lane];
            float r2 = h2[(qa.z << 6) + lane], r3 = h2[(qa.w << 6) + lane];
            float r4 = h2[(qb.x << 6) + lane], r5 = h2[(qb.y << 6) + lane];
            float r6 = h2[(qb.z << 6) + lane], r7 = h2[(qb.w << 6) + lane];
            acc += ((r0 + r1) + (r2 + r3)) + ((r4 + r5) + (r6 + r7));
        }
        float z = fmaxf(fmaf(dinv[un], acc, bz), 0.0f);
        atomicAdd(&gsum[(batch[un] << 6) + lane], z);
    }
}

// ---------------- head ----------------
__global__ void head_kernel(const float* __restrict__ gsum, const int* __restrict__ gstart,
                            const float* __restrict__ Wf1, const float* __restrict__ bf1,
                            const float* __restrict__ Wf2, const float* __restrict__ bf2,
                            float* __restrict__ out) {
    __shared__ float gs[HID];
    __shared__ float ts[HID];
    int b = blockIdx.x;
    int j = threadIdx.x;
    float cnt = fmaxf((float)(gstart[b + 1] - gstart[b]), 1.0f);
    gs[j] = gsum[b * HID + j] / cnt;
    __syncthreads();
    float acc = bf1[j];
#pragma unroll
    for (int k = 0; k < HID; ++k) acc = fmaf(gs[k], Wf1[k * HID + j], acc);
    ts[j] = fmaxf(acc, 0.0f);
    __syncthreads();
    if (j < 4) {
        float o = bf2[j];
#pragma unroll
        for (int k = 0; k < HID; ++k) o = fmaf(ts[k], Wf2[k * 4 + j], o);
        out[b * 4 + j] = o;
    }
}

extern "C" void kernel_launch(void* const* d_in, const int* in_sizes, int n_in,
                              void* d_out, int out_size, void* d_ws, size_t ws_size,
                              hipStream_t stream) {
    const float* x   = (const float*)d_in[0];
    const int*   ei  = (const int*)d_in[1];
    const int*   bat = (const int*)d_in[2];
    const float* W1  = (const float*)d_in[4];
    const float* b1  = (const float*)d_in[5];
    const float* W2  = (const float*)d_in[6];
    const float* b2  = (const float*)d_in[7];
    const float* Wf1 = (const float*)d_in[8];
    const float* bf1 = (const float*)d_in[9];
    const float* Wf2 = (const float*)d_in[10];
    const float* bf2 = (const float*)d_in[11];
    float* out = (float*)d_out;

    int N = in_sizes[2];
    int E = in_sizes[1] / 2;
    const int* src = ei;
    const int* dst = ei + E;
    int nb = (N + 255) / 256;
    size_t Ecap = ((size_t)E + 7 * (size_t)N + 8 + 3) & ~(size_t)3;  // padded upper bound, x4
    int n4 = (int)(Ecap / 4);

    char* ws = (char*)d_ws;
    size_t off = 0;
    auto alloc = [&](size_t bytes) {
        char* p = ws + off;
        off = (off + bytes + 255) & ~(size_t)255;
        return p;
    };
    int*    deg    = (int*)alloc((size_t)N * 4);
    int*    cur    = (int*)alloc((size_t)N * 4);
    float*  dinv   = (float*)alloc((size_t)N * 4);
    int*    rowptr = (int*)alloc((size_t)(N + 1) * 4);
    int*    bsum   = (int*)alloc((size_t)nb * 4);
    int*    bofs   = (int*)alloc((size_t)nb * 4);
    int*    esrc   = (int*)alloc(Ecap * 4);
    float2* xs2    = (float2*)alloc((size_t)(N + 1) * 8);
    float*  h2buf  = (float*)alloc((size_t)(N + 1) * HID * 4);
    float*  gsum   = (float*)alloc((size_t)NG * HID * 4);
    int*    gstart = (int*)alloc((size_t)(NG + 1) * 4);

    hipMemsetAsync(deg, 0, (size_t)((char*)cur - (char*)deg) + (size_t)N * 4, stream);
    hipMemsetAsync(gsum, 0, (size_t)NG * HID * 4, stream);

    deg_kernel<<<(E + 255) / 256, 256, 0, stream>>>(dst, deg, E);
    fill_esrc_kernel<<<(n4 + 255) / 256, 256, 0, stream>>>((int4*)esrc, N, n4);
    gstart_kernel<<<(N + 255) / 256, 256, 0, stream>>>(bat, gstart, N);
    block_sums_kernel<<<nb, 256, 0, stream>>>(deg, bsum, N);
    scan_bsum_kernel<<<1, 1024, 0, stream>>>(bsum, bofs, nb);
    scan_block_kernel<<<nb, 256, 0, stream>>>(deg, bofs, (const float2*)x, rowptr, dinv,
                                              xs2, N);
    bucket_kernel<<<(E + 255) / 256, 256, 0, stream>>>(src, dst, rowptr, cur, esrc, E);

    // layer 1 (+ fused W2): h2 = (relu((A xs)@W1 + b1) * dinv) @ W2   (+ zero pad row)
    int nh = (N + 1) * HID;
    layer1_kernel<<<(nh + 255) / 256, 256, 0, stream>>>(xs2, rowptr, esrc, dinv, W1, b1,
                                                        W2, h2buf, N);

    // layer 2: pure gather-sum -> relu -> pool
    layer2_kernel<<<8192, 256, 0, stream>>>(rowptr, esrc, dinv, h2buf, b2, bat, gsum, N);

    head_kernel<<<NG, HID, 0, stream>>>(gsum, gstart, Wf1, bf1, Wf2, bf2, out);
}